// Round 15
// baseline (120.895 us; speedup 1.0000x reference)
//
#include <hip/hip_runtime.h>
#include <hip/hip_bf16.h>

// B=2, S=2048, E=1024, H=16, D=64. f32 in/out; bf16 MFMA internally.
// R14: attn = R11-exact body (proven 49.9us) + LDS pitches changed from
//      stride=4 (mod 32 dwords) to stride=2: Ks/Ps pitch 72->68, Vt 136->132.
//      Row-starts spread over 32 banks instead of 8 -> 4-way write/read
//      conflicts become <=2-way (free). GEMMs (R11 BK=64 split), prep unchanged.

typedef __bf16 bf16;
typedef __bf16 bf16x4 __attribute__((ext_vector_type(4)));
typedef __bf16 bf16x8 __attribute__((ext_vector_type(8)));
typedef float  f32x4  __attribute__((ext_vector_type(4)));

#define MNEG (-1.0e30f)
#define QSCALE 0.1803368801f   // 0.125 * log2(e): folded into Q at GEMM1 epilogue

__device__ __forceinline__ void gload16(const bf16* g, bf16* l) {
  __builtin_amdgcn_global_load_lds((const __attribute__((address_space(1))) void*)g,
                                   (__attribute__((address_space(3))) void*)l, 16, 0, 0);
}

// ---------------- fused prep: x cvt (blocks 0..2047), W_attn^T, W_proj^T ----------------
__global__ __launch_bounds__(256) void prep_k(const float* __restrict__ x, bf16* __restrict__ xb,
                                              const float* __restrict__ Wa, bf16* __restrict__ WaT,
                                              const float* __restrict__ Wp, bf16* __restrict__ WpT) {
  const int bid = blockIdx.x;
  if (bid < 2048) {
    const int i = bid * 256 + threadIdx.x;
    f32x4 a = ((const f32x4*)x)[2 * i], b = ((const f32x4*)x)[2 * i + 1];
    bf16x8 o;
    for (int j = 0; j < 4; ++j) { o[j] = (bf16)a[j]; o[4 + j] = (bf16)b[j]; }
    ((bf16x8*)xb)[i] = o;
    return;
  }
  __shared__ bf16 t[64][68];
  const float* in; bf16* out; int C, cx, cy;
  if (bid < 2816) { in = Wa; out = WaT; C = 3072; const int tt = bid - 2048; cx = tt % 48; cy = tt / 48; }
  else            { in = Wp; out = WpT; C = 1024; const int tt = bid - 2816; cx = tt % 16; cy = tt / 16; }
  const int R = 1024;
  const int c0 = cx * 64, r0 = cy * 64;
  const int lr = threadIdx.x >> 4;
  const int lc = (threadIdx.x & 15) * 4;
  for (int i = 0; i < 4; ++i) {
    int r = lr + i * 16;
    f32x4 v = *(const f32x4*)(in + (size_t)(r0 + r) * C + c0 + lc);
    bf16x4 b;
    for (int j = 0; j < 4; ++j) b[j] = (bf16)v[j];
    *(bf16x4*)&t[r][lc] = b;
  }
  __syncthreads();
  for (int i = 0; i < 4; ++i) {
    int c = lr + i * 16;
    bf16x4 v;
    for (int j = 0; j < 4; ++j) v[j] = t[lc + j][c];
    *(bf16x4*)(out + (size_t)(c0 + c) * R + r0 + lc) = v;
  }
}

// ---------------- GEMM: C[M,N] = A[M,K]*Bt[N,K]^T + bias (bf16 in, f32 acc) ----------------
// BK=64 via split arrays (each half keeps 64B row stride: conflict-free, linear for gload_lds).
template <int MODE, int BN>
__global__ __launch_bounds__(256) void gemm_bt(const bf16* __restrict__ A,
                                               const bf16* __restrict__ Bt,
                                               const float* __restrict__ bias,
                                               float* __restrict__ C,
                                               bf16* __restrict__ Qo,
                                               bf16* __restrict__ Ko,
                                               bf16* __restrict__ Vo,
                                               int M, int N, int K) {
  constexpr int NT = BN / 32;
  __shared__ bf16 As0[128 * 32], As1[128 * 32];
  __shared__ bf16 Bs0[BN * 32],  Bs1[BN * 32];
  const int tid = threadIdx.x;
  const int w = tid >> 6, l = tid & 63;
  const int nx = gridDim.x;
  const int nwg = nx * gridDim.y;
  const int flat = blockIdx.y * nx + blockIdx.x;
  const int swz = (flat & 7) * (nwg >> 3) + (flat >> 3);
  const int m0 = (swz / nx) * 128, n0 = (swz % nx) * BN;
  const int wm = w >> 1, wn = w & 1;
  const int fr = l & 15, fg = l >> 4;
  const int srow = l >> 2;
  const int scol = (l & 3) * 8;

  f32x4 acc[4][NT] = {};

  for (int k0 = 0; k0 < K; k0 += 64) {
    __syncthreads();
    for (int c = 0; c < 2; ++c) {
      const int rowA = 32 * w + 16 * c + srow;
      gload16(A + (size_t)(m0 + rowA) * K + k0 + scol,      As0 + (32 * w + 16 * c) * 32);
      gload16(A + (size_t)(m0 + rowA) * K + k0 + 32 + scol, As1 + (32 * w + 16 * c) * 32);
    }
    for (int c = 0; c < BN / 64; ++c) {
      const int rb = (BN / 64) * 16 * w + 16 * c;
      gload16(Bt + (size_t)(n0 + rb + srow) * K + k0 + scol,      Bs0 + rb * 32);
      gload16(Bt + (size_t)(n0 + rb + srow) * K + k0 + 32 + scol, Bs1 + rb * 32);
    }
    __syncthreads();

    bf16x8 af[4][2], bfv[NT][2];
    for (int mt = 0; mt < 4; ++mt) {
      af[mt][0] = *(const bf16x8*)(As0 + (wm * 64 + mt * 16 + fr) * 32 + 8 * fg);
      af[mt][1] = *(const bf16x8*)(As1 + (wm * 64 + mt * 16 + fr) * 32 + 8 * fg);
    }
    for (int nt = 0; nt < NT; ++nt) {
      bfv[nt][0] = *(const bf16x8*)(Bs0 + (wn * (BN / 2) + nt * 16 + fr) * 32 + 8 * fg);
      bfv[nt][1] = *(const bf16x8*)(Bs1 + (wn * (BN / 2) + nt * 16 + fr) * 32 + 8 * fg);
    }
    for (int mt = 0; mt < 4; ++mt)
      for (int nt = 0; nt < NT; ++nt) {
        acc[mt][nt] = __builtin_amdgcn_mfma_f32_16x16x32_bf16(af[mt][0], bfv[nt][0], acc[mt][nt], 0, 0, 0);
        acc[mt][nt] = __builtin_amdgcn_mfma_f32_16x16x32_bf16(af[mt][1], bfv[nt][1], acc[mt][nt], 0, 0, 0);
      }
  }

  for (int mt = 0; mt < 4; ++mt) {
    for (int nt = 0; nt < NT; ++nt) {
      const int row0 = m0 + wm * 64 + mt * 16 + 4 * fg;
      const int col = n0 + wn * (BN / 2) + nt * 16 + fr;
      const float bv = bias[col];
      if (MODE == 0) {
        for (int r = 0; r < 4; ++r)
          C[(size_t)(row0 + r) * N + col] = acc[mt][nt][r] + bv;
      } else {
        const int which = col >> 10, h = (col >> 6) & 15, d = col & 63;
        const int b = row0 >> 11, s = row0 & 2047;
        if (which == 2) {
          bf16x4 vv;
          for (int r = 0; r < 4; ++r) vv[r] = (bf16)(acc[mt][nt][r] + bv);
          *(bf16x4*)(Vo + ((size_t)(b * 16 + h) * 64 + d) * 2048 + s) = vv;
        } else if (which == 0) {
          for (int r = 0; r < 4; ++r)
            Qo[((size_t)(b * 16 + h) * 2048 + s + r) * 64 + d] =
                (bf16)((acc[mt][nt][r] + bv) * QSCALE);
        } else {
          for (int r = 0; r < 4; ++r)
            Ko[((size_t)(b * 16 + h) * 2048 + s + r) * 64 + d] = (bf16)(acc[mt][nt][r] + bv);
        }
      }
    }
  }
}

// ---------------- flash attention: one 64-row q-tile per block, heavy-first ----------------
// grid 1024: bh = 4*(bid&7)+((bid>>3)&3) (XCD spread, KV L2-resident);
// qt = 31 - (bid>>5) heavy-first. KVBLK=128 staged, T14 prefetch, no-max exp2 softmax.
// Pitches: Ks/Ps 68, Vt 132 (row stride = 2 mod 32 dwords -> <=2-way bank aliasing).
__global__ __launch_bounds__(256, 3) void attn_k(const bf16* __restrict__ Qw,
                                                 const bf16* __restrict__ Kw,
                                                 const bf16* __restrict__ VtG,
                                                 bf16* __restrict__ AO) {
  __shared__ bf16 Ks[128 * 68];        // K tile [k][d]            17408 B
  __shared__ bf16 Vt[64 * 132];        // V^T tile [d][k 0..127]   16896 B
  __shared__ bf16 Ps[4 * 16 * 68];     // per-wave P                8704 B
  const int tid = threadIdx.x, w = tid >> 6, l = tid & 63;
  const int bid = blockIdx.x;
  const int bh = ((bid & 7) << 2) | ((bid >> 3) & 3);
  const int qt = 31 - (bid >> 5);             // heavy-first
  const int q0 = qt * 64;
  const int fr = l & 15, fg = l >> 4;
  const size_t base = (size_t)bh * 2048 * 64;
  const int qw0 = q0 + w * 16;
  const int q = qw0 + fr;
  bf16* Pw = Ps + w * 16 * 68;
  const int r8 = tid >> 3, c8 = (tid & 7) * 8;
  const int r16 = tid >> 4, c16 = (tid & 15) * 8;

  bf16x8 qf[2];
  for (int t = 0; t < 2; ++t)
    qf[t] = *(const bf16x8*)(Qw + base + (size_t)(qw0 + fr) * 64 + 32 * t + 8 * fg);

  f32x4 oacc[4] = {};
  float lsum = 0.f;
  bf16x8 kreg[4], vreg[4];

  auto load_tile = [&](int kt) {   // 128 keys; tail overshoot stays in ws, never consumed
    for (int c = 0; c < 4; ++c) {
      kreg[c] = *(const bf16x8*)(Kw + base + (size_t)(kt + r8 + 32 * c) * 64 + c8);
      vreg[c] = *(const bf16x8*)(VtG + base + (size_t)(r16 + 16 * c) * 2048 + kt + c16);
    }
  };
  auto write_tile = [&]() {
    for (int c = 0; c < 4; ++c) {
      *(bf16x8*)(Ks + (r8 + 32 * c) * 68 + c8) = kreg[c];
      *(bf16x8*)(Vt + (r16 + 16 * c) * 132 + c16) = vreg[c];
    }
  };

  load_tile(0);
  write_tile();
  __syncthreads();

  for (int kt = 0; kt <= q0; kt += 128) {
    const bool havenext = (kt + 128 <= q0);
    if (havenext) load_tile(kt + 128);      // T14: issue early

    for (int h = 0; h < 2; ++h) {
      const int kh = kt + 64 * h;
      if (kh > q0) break;

      // QK^T: St[k][q], 4 k-subtiles of 16
      f32x4 sc[4];
      __builtin_amdgcn_s_setprio(1);
      for (int c = 0; c < 4; ++c) {
        bf16x8 kf0 = *(const bf16x8*)(Ks + (64 * h + c * 16 + fr) * 68 + 8 * fg);
        bf16x8 kf1 = *(const bf16x8*)(Ks + (64 * h + c * 16 + fr) * 68 + 32 + 8 * fg);
        f32x4 z = {};
        z = __builtin_amdgcn_mfma_f32_16x16x32_bf16(kf0, qf[0], z, 0, 0, 0);
        sc[c] = __builtin_amdgcn_mfma_f32_16x16x32_bf16(kf1, qf[1], z, 0, 0, 0);
      }
      __builtin_amdgcn_s_setprio(0);

      // softmax (no max) -> P (all 4 sub-tiles), lane-local sum   [R11-exact]
      const bool need_mask = (kh + 63 > qw0);
      float psum = 0.f;
      for (int c = 0; c < 4; ++c) {
        bf16x4 pb;
        for (int r = 0; r < 4; ++r) {
          float s = sc[c][r];
          if (need_mask && (kh + c * 16 + 4 * fg + r > q)) s = MNEG;
          const float pv = __builtin_amdgcn_exp2f(s);
          psum += pv;
          pb[r] = (bf16)pv;
        }
        *(bf16x4*)(Pw + fr * 68 + c * 16 + 4 * fg) = pb;
      }
      psum += __shfl_xor(psum, 16, 64);
      psum += __shfl_xor(psum, 32, 64);
      lsum += psum;

      asm volatile("" ::: "memory");   // P writes before P reads (in-wave DS order)
      __builtin_amdgcn_s_setprio(1);
      for (int t = 0; t < 2; ++t) {
        bf16x8 pa = *(const bf16x8*)(Pw + fr * 68 + 32 * t + 8 * fg);
        for (int dt = 0; dt < 4; ++dt) {
          bf16x8 vf = *(const bf16x8*)(Vt + (dt * 16 + fr) * 132 + 64 * h + 32 * t + 8 * fg);
          oacc[dt] = __builtin_amdgcn_mfma_f32_16x16x32_bf16(pa, vf, oacc[dt], 0, 0, 0);
        }
      }
      __builtin_amdgcn_s_setprio(0);
      asm volatile("" ::: "memory");   // Pw reused next half
    }

    if (!havenext) break;
    __syncthreads();
    write_tile();                           // T14: write-late
    __syncthreads();
  }

  const int b = bh >> 4, h = bh & 15;
  float linv[4];
  for (int r = 0; r < 4; ++r)
    linv[r] = 1.f / __shfl(lsum, (l & 48) | (4 * fg + r), 64);
  for (int dt = 0; dt < 4; ++dt)
    for (int r = 0; r < 4; ++r) {
      const int qq = qw0 + 4 * fg + r;
      AO[(size_t)(b * 2048 + qq) * 1024 + h * 64 + dt * 16 + fr] =
          (bf16)(oacc[dt][r] * linv[r]);
    }
}

// ---------------- launch ----------------
extern "C" void kernel_launch(void* const* d_in, const int* in_sizes, int n_in,
                              void* d_out, int out_size, void* d_ws, size_t ws_size,
                              hipStream_t stream) {
  const float* x      = (const float*)d_in[0];
  const float* W_attn = (const float*)d_in[1];
  const float* b_attn = (const float*)d_in[2];
  const float* W_proj = (const float*)d_in[3];
  const float* b_proj = (const float*)d_in[4];
  float* out = (float*)d_out;

  char* ws = (char*)d_ws;
  bf16* WaT = (bf16*)(ws);                 // 6291456 B
  bf16* WpT = (bf16*)(ws + 6291456);       // 2097152 B
  bf16* Qw  = (bf16*)(ws + 8388608);       // [B,H,S,D] (pre-scaled by QSCALE)
  bf16* Kw  = (bf16*)(ws + 16777216);      // [B,H,S,D]
  bf16* VtG = (bf16*)(ws + 25165824);      // [B,H,D,S]
  bf16* AO  = (bf16*)(ws + 33554432);      // [B,S,E] bf16; aliased as xb pre-attn
  bf16* xb  = AO;

  prep_k<<<3072, 256, 0, stream>>>(x, xb, W_attn, WaT, W_proj, WpT);

  gemm_bt<1, 128><<<dim3(24, 32), 256, 0, stream>>>(
      xb, WaT, b_attn, nullptr, Qw, Kw, VtG, 4096, 3072, 1024);

  attn_k<<<1024, 256, 0, stream>>>(Qw, Kw, VtG, AO);

  gemm_bt<0, 64><<<dim3(16, 32), 256, 0, stream>>>(
      AO, WpT, b_proj, out, nullptr, nullptr, nullptr, 4096, 1024, 1024);
}

// Round 16
// 116.017 us; speedup vs baseline: 1.0420x; 1.0420x over previous
//
#include <hip/hip_runtime.h>
#include <hip/hip_bf16.h>

// B=2, S=2048, E=1024, H=16, D=64. f32 in/out; bf16 MFMA internally.
// R15: attn = R11-exact body (pitch 72/136, proven 49.9us) + DETERMINISTIC split-K
//      for heavy q-tiles (qt>=16): two K-halves write disjoint f32 partials (plain
//      stores, no atomics/memset); norm kernel combines. Light tiles write AO direct.
//      GEMMs (R11 BK=64 split) and prep unchanged.

typedef __bf16 bf16;
typedef __bf16 bf16x4 __attribute__((ext_vector_type(4)));
typedef __bf16 bf16x8 __attribute__((ext_vector_type(8)));
typedef float  f32x4  __attribute__((ext_vector_type(4)));

#define MNEG (-1.0e30f)
#define QSCALE 0.1803368801f   // 0.125 * log2(e): folded into Q at GEMM1 epilogue

__device__ __forceinline__ void gload16(const bf16* g, bf16* l) {
  __builtin_amdgcn_global_load_lds((const __attribute__((address_space(1))) void*)g,
                                   (__attribute__((address_space(3))) void*)l, 16, 0, 0);
}

// ---------------- fused prep: x cvt (blocks 0..2047), W_attn^T, W_proj^T ----------------
__global__ __launch_bounds__(256) void prep_k(const float* __restrict__ x, bf16* __restrict__ xb,
                                              const float* __restrict__ Wa, bf16* __restrict__ WaT,
                                              const float* __restrict__ Wp, bf16* __restrict__ WpT) {
  const int bid = blockIdx.x;
  if (bid < 2048) {
    const int i = bid * 256 + threadIdx.x;
    f32x4 a = ((const f32x4*)x)[2 * i], b = ((const f32x4*)x)[2 * i + 1];
    bf16x8 o;
    for (int j = 0; j < 4; ++j) { o[j] = (bf16)a[j]; o[4 + j] = (bf16)b[j]; }
    ((bf16x8*)xb)[i] = o;
    return;
  }
  __shared__ bf16 t[64][68];
  const float* in; bf16* out; int C, cx, cy;
  if (bid < 2816) { in = Wa; out = WaT; C = 3072; const int tt = bid - 2048; cx = tt % 48; cy = tt / 48; }
  else            { in = Wp; out = WpT; C = 1024; const int tt = bid - 2816; cx = tt % 16; cy = tt / 16; }
  const int R = 1024;
  const int c0 = cx * 64, r0 = cy * 64;
  const int lr = threadIdx.x >> 4;
  const int lc = (threadIdx.x & 15) * 4;
  for (int i = 0; i < 4; ++i) {
    int r = lr + i * 16;
    f32x4 v = *(const f32x4*)(in + (size_t)(r0 + r) * C + c0 + lc);
    bf16x4 b;
    for (int j = 0; j < 4; ++j) b[j] = (bf16)v[j];
    *(bf16x4*)&t[r][lc] = b;
  }
  __syncthreads();
  for (int i = 0; i < 4; ++i) {
    int c = lr + i * 16;
    bf16x4 v;
    for (int j = 0; j < 4; ++j) v[j] = t[lc + j][c];
    *(bf16x4*)(out + (size_t)(c0 + c) * R + r0 + lc) = v;
  }
}

// ---------------- GEMM: C[M,N] = A[M,K]*Bt[N,K]^T + bias (bf16 in, f32 acc) ----------------
template <int MODE, int BN>
__global__ __launch_bounds__(256) void gemm_bt(const bf16* __restrict__ A,
                                               const bf16* __restrict__ Bt,
                                               const float* __restrict__ bias,
                                               float* __restrict__ C,
                                               bf16* __restrict__ Qo,
                                               bf16* __restrict__ Ko,
                                               bf16* __restrict__ Vo,
                                               int M, int N, int K) {
  constexpr int NT = BN / 32;
  __shared__ bf16 As0[128 * 32], As1[128 * 32];
  __shared__ bf16 Bs0[BN * 32],  Bs1[BN * 32];
  const int tid = threadIdx.x;
  const int w = tid >> 6, l = tid & 63;
  const int nx = gridDim.x;
  const int nwg = nx * gridDim.y;
  const int flat = blockIdx.y * nx + blockIdx.x;
  const int swz = (flat & 7) * (nwg >> 3) + (flat >> 3);
  const int m0 = (swz / nx) * 128, n0 = (swz % nx) * BN;
  const int wm = w >> 1, wn = w & 1;
  const int fr = l & 15, fg = l >> 4;
  const int srow = l >> 2;
  const int scol = (l & 3) * 8;

  f32x4 acc[4][NT] = {};

  for (int k0 = 0; k0 < K; k0 += 64) {
    __syncthreads();
    for (int c = 0; c < 2; ++c) {
      const int rowA = 32 * w + 16 * c + srow;
      gload16(A + (size_t)(m0 + rowA) * K + k0 + scol,      As0 + (32 * w + 16 * c) * 32);
      gload16(A + (size_t)(m0 + rowA) * K + k0 + 32 + scol, As1 + (32 * w + 16 * c) * 32);
    }
    for (int c = 0; c < BN / 64; ++c) {
      const int rb = (BN / 64) * 16 * w + 16 * c;
      gload16(Bt + (size_t)(n0 + rb + srow) * K + k0 + scol,      Bs0 + rb * 32);
      gload16(Bt + (size_t)(n0 + rb + srow) * K + k0 + 32 + scol, Bs1 + rb * 32);
    }
    __syncthreads();

    bf16x8 af[4][2], bfv[NT][2];
    for (int mt = 0; mt < 4; ++mt) {
      af[mt][0] = *(const bf16x8*)(As0 + (wm * 64 + mt * 16 + fr) * 32 + 8 * fg);
      af[mt][1] = *(const bf16x8*)(As1 + (wm * 64 + mt * 16 + fr) * 32 + 8 * fg);
    }
    for (int nt = 0; nt < NT; ++nt) {
      bfv[nt][0] = *(const bf16x8*)(Bs0 + (wn * (BN / 2) + nt * 16 + fr) * 32 + 8 * fg);
      bfv[nt][1] = *(const bf16x8*)(Bs1 + (wn * (BN / 2) + nt * 16 + fr) * 32 + 8 * fg);
    }
    for (int mt = 0; mt < 4; ++mt)
      for (int nt = 0; nt < NT; ++nt) {
        acc[mt][nt] = __builtin_amdgcn_mfma_f32_16x16x32_bf16(af[mt][0], bfv[nt][0], acc[mt][nt], 0, 0, 0);
        acc[mt][nt] = __builtin_amdgcn_mfma_f32_16x16x32_bf16(af[mt][1], bfv[nt][1], acc[mt][nt], 0, 0, 0);
      }
  }

  for (int mt = 0; mt < 4; ++mt) {
    for (int nt = 0; nt < NT; ++nt) {
      const int row0 = m0 + wm * 64 + mt * 16 + 4 * fg;
      const int col = n0 + wn * (BN / 2) + nt * 16 + fr;
      const float bv = bias[col];
      if (MODE == 0) {
        for (int r = 0; r < 4; ++r)
          C[(size_t)(row0 + r) * N + col] = acc[mt][nt][r] + bv;
      } else {
        const int which = col >> 10, h = (col >> 6) & 15, d = col & 63;
        const int b = row0 >> 11, s = row0 & 2047;
        if (which == 2) {
          bf16x4 vv;
          for (int r = 0; r < 4; ++r) vv[r] = (bf16)(acc[mt][nt][r] + bv);
          *(bf16x4*)(Vo + ((size_t)(b * 16 + h) * 64 + d) * 2048 + s) = vv;
        } else if (which == 0) {
          for (int r = 0; r < 4; ++r)
            Qo[((size_t)(b * 16 + h) * 2048 + s + r) * 64 + d] =
                (bf16)((acc[mt][nt][r] + bv) * QSCALE);
        } else {
          for (int r = 0; r < 4; ++r)
            Ko[((size_t)(b * 16 + h) * 2048 + s + r) * 64 + d] = (bf16)(acc[mt][nt][r] + bv);
        }
      }
    }
  }
}

// ---------------- flash attention, R11 body + heavy-half deterministic split-K ----------------
// SPLIT=1 grid 1536: bid<1024 -> heavy halves (qt 16..31, part 0/1); else light (qt 15..0).
// SPLIT=0 grid 1024: all tiles direct (R11-exact). No-max exp2 softmax => partials add.
template <int SPLIT>
__global__ __launch_bounds__(256, 3) void attn_k(const bf16* __restrict__ Qw,
                                                 const bf16* __restrict__ Kw,
                                                 const bf16* __restrict__ VtG,
                                                 bf16* __restrict__ AO,
                                                 float* __restrict__ Op,
                                                 float* __restrict__ Lp) {
  __shared__ bf16 Ks[128 * 72];        // K tile [k][d]            18432 B
  __shared__ bf16 Vt[64 * 136];        // V^T tile [d][k 0..127]   17408 B
  __shared__ bf16 Ps[4 * 16 * 72];     // per-wave P                9216 B
  const int tid = threadIdx.x, w = tid >> 6, l = tid & 63;
  const int bid = blockIdx.x;

  int bh, qt, part; bool heavy;
  if (SPLIT && bid < 1024) {
    bh = ((bid & 7) << 2) | ((bid >> 3) & 3);
    const int rem = bid >> 5;            // 0..31
    qt = 31 - (rem >> 1);                // 31..16, heavy-first
    part = rem & 1;
    heavy = true;
  } else {
    const int r = SPLIT ? bid - 1024 : bid;
    bh = ((r & 7) << 2) | ((r >> 3) & 3);
    qt = (SPLIT ? 15 : 31) - (r >> 5);
    part = 0;
    heavy = false;
  }

  const int q0 = qt * 64;
  const int nt = (qt >> 1) + 1;          // number of 128-key rounds
  int ktbeg = 0, ktend = q0;             // ktend = last round start (inner h-loop guards kh<=q0)
  if (heavy) {
    const int lo = (nt + 1) >> 1;        // rounds in part 0
    if (part == 0) { ktbeg = 0;        ktend = (lo - 1) * 128; }
    else           { ktbeg = lo * 128; ktend = (nt - 1) * 128; }
  }

  const int fr = l & 15, fg = l >> 4;
  const size_t base = (size_t)bh * 2048 * 64;
  const int qw0 = q0 + w * 16;
  const int q = qw0 + fr;
  bf16* Pw = Ps + w * 16 * 72;
  const int r8 = tid >> 3, c8 = (tid & 7) * 8;
  const int r16 = tid >> 4, c16 = (tid & 15) * 8;

  bf16x8 qf[2];
  for (int t = 0; t < 2; ++t)
    qf[t] = *(const bf16x8*)(Qw + base + (size_t)(qw0 + fr) * 64 + 32 * t + 8 * fg);

  f32x4 oacc[4] = {};
  float lsum = 0.f;
  bf16x8 kreg[4], vreg[4];

  auto load_tile = [&](int kt) {   // tail overshoot stays in ws, never consumed
    for (int c = 0; c < 4; ++c) {
      kreg[c] = *(const bf16x8*)(Kw + base + (size_t)(kt + r8 + 32 * c) * 64 + c8);
      vreg[c] = *(const bf16x8*)(VtG + base + (size_t)(r16 + 16 * c) * 2048 + kt + c16);
    }
  };
  auto write_tile = [&]() {
    for (int c = 0; c < 4; ++c) {
      *(bf16x8*)(Ks + (r8 + 32 * c) * 72 + c8) = kreg[c];
      *(bf16x8*)(Vt + (r16 + 16 * c) * 136 + c16) = vreg[c];
    }
  };

  load_tile(ktbeg);
  write_tile();
  __syncthreads();

  for (int kt = ktbeg; kt <= ktend; kt += 128) {
    const bool havenext = (kt + 128 <= ktend);
    if (havenext) load_tile(kt + 128);      // T14: issue early

    for (int h = 0; h < 2; ++h) {
      const int kh = kt + 64 * h;
      if (kh > q0) break;

      // QK^T: St[k][q], 4 k-subtiles of 16
      f32x4 sc[4];
      __builtin_amdgcn_s_setprio(1);
      for (int c = 0; c < 4; ++c) {
        bf16x8 kf0 = *(const bf16x8*)(Ks + (64 * h + c * 16 + fr) * 72 + 8 * fg);
        bf16x8 kf1 = *(const bf16x8*)(Ks + (64 * h + c * 16 + fr) * 72 + 32 + 8 * fg);
        f32x4 z = {};
        z = __builtin_amdgcn_mfma_f32_16x16x32_bf16(kf0, qf[0], z, 0, 0, 0);
        sc[c] = __builtin_amdgcn_mfma_f32_16x16x32_bf16(kf1, qf[1], z, 0, 0, 0);
      }
      __builtin_amdgcn_s_setprio(0);

      // softmax (no max) -> P, lane-local sum   [R11-exact]
      const bool need_mask = (kh + 63 > qw0);
      float psum = 0.f;
      for (int c = 0; c < 4; ++c) {
        bf16x4 pb;
        for (int r = 0; r < 4; ++r) {
          float s = sc[c][r];
          if (need_mask && (kh + c * 16 + 4 * fg + r > q)) s = MNEG;
          const float pv = __builtin_amdgcn_exp2f(s);
          psum += pv;
          pb[r] = (bf16)pv;
        }
        *(bf16x4*)(Pw + fr * 72 + c * 16 + 4 * fg) = pb;
      }
      psum += __shfl_xor(psum, 16, 64);
      psum += __shfl_xor(psum, 32, 64);
      lsum += psum;

      asm volatile("" ::: "memory");   // P writes before P reads (in-wave DS order)
      __builtin_amdgcn_s_setprio(1);
      for (int t = 0; t < 2; ++t) {
        bf16x8 pa = *(const bf16x8*)(Pw + fr * 72 + 32 * t + 8 * fg);
        for (int dt = 0; dt < 4; ++dt) {
          bf16x8 vf = *(const bf16x8*)(Vt + (dt * 16 + fr) * 136 + 64 * h + 32 * t + 8 * fg);
          oacc[dt] = __builtin_amdgcn_mfma_f32_16x16x32_bf16(pa, vf, oacc[dt], 0, 0, 0);
        }
      }
      __builtin_amdgcn_s_setprio(0);
      asm volatile("" ::: "memory");   // Pw reused next half
    }

    if (!havenext) break;
    __syncthreads();
    write_tile();                           // T14: write-late
    __syncthreads();
  }

  if (heavy) {
    // plain stores of partials (disjoint per part) — deterministic combine in norm_k
    const size_t pb = ((size_t)part * 32 + bh) * 1024;     // row base within part
    const int sl0 = qw0 - 1024;
    for (int dt = 0; dt < 4; ++dt)
      for (int r = 0; r < 4; ++r)
        Op[(pb + sl0 + 4 * fg + r) * 64 + dt * 16 + fr] = oacc[dt][r];
    if (fg == 0) Lp[pb + sl0 + fr] = lsum;
  } else {
    const int b = bh >> 4, h = bh & 15;
    float linv[4];
    for (int r = 0; r < 4; ++r)
      linv[r] = 1.f / __shfl(lsum, (l & 48) | (4 * fg + r), 64);
    for (int dt = 0; dt < 4; ++dt)
      for (int r = 0; r < 4; ++r) {
        const int qq = qw0 + 4 * fg + r;
        AO[(size_t)(b * 2048 + qq) * 1024 + h * 64 + dt * 16 + fr] =
            (bf16)(oacc[dt][r] * linv[r]);
      }
  }
}

// ---------------- norm: combine 2 partials for heavy rows (s in [1024,2048)) ----------------
__global__ __launch_bounds__(256) void norm_k(const float* __restrict__ Op,
                                              const float* __restrict__ Lp,
                                              bf16* __restrict__ AO) {
  const int i = blockIdx.x * 256 + threadIdx.x;   // 262144 threads
  const int d0 = (i & 7) * 8;
  const int sl = (i >> 3) & 1023;
  const int h  = (i >> 13) & 15;
  const int b  = i >> 17;
  const size_t bhs = ((size_t)(b * 16 + h)) * 1024 + sl;
  const size_t PSTR = (size_t)32 * 1024;           // Lp part stride (rows)
  const float linv = 1.f / (Lp[bhs] + Lp[PSTR + bhs]);
  const float* o0 = Op + bhs * 64 + d0;
  const float* o1 = Op + PSTR * 64 + bhs * 64 + d0;
  f32x4 a0 = *(const f32x4*)o0, a1 = *(const f32x4*)(o0 + 4);
  f32x4 b0 = *(const f32x4*)o1, b1 = *(const f32x4*)(o1 + 4);
  bf16x8 o;
  for (int j = 0; j < 4; ++j) {
    o[j]     = (bf16)((a0[j] + b0[j]) * linv);
    o[4 + j] = (bf16)((a1[j] + b1[j]) * linv);
  }
  *(bf16x8*)(AO + ((size_t)(b * 2048) + 1024 + sl) * 1024 + h * 64 + d0) = o;
}

// ---------------- launch ----------------
extern "C" void kernel_launch(void* const* d_in, const int* in_sizes, int n_in,
                              void* d_out, int out_size, void* d_ws, size_t ws_size,
                              hipStream_t stream) {
  const float* x      = (const float*)d_in[0];
  const float* W_attn = (const float*)d_in[1];
  const float* b_attn = (const float*)d_in[2];
  const float* W_proj = (const float*)d_in[3];
  const float* b_proj = (const float*)d_in[4];
  float* out = (float*)d_out;

  char* ws = (char*)d_ws;
  bf16* WaT = (bf16*)(ws);                 // 6291456 B
  bf16* WpT = (bf16*)(ws + 6291456);       // 2097152 B
  bf16* Qw  = (bf16*)(ws + 8388608);       // [B,H,S,D] (pre-scaled by QSCALE)
  bf16* Kw  = (bf16*)(ws + 16777216);      // [B,H,S,D]
  bf16* VtG = (bf16*)(ws + 25165824);      // [B,H,D,S]
  bf16* AO  = (bf16*)(ws + 33554432);      // [B,S,E] bf16; aliased as xb pre-attn
  bf16* xb  = AO;
  float* Op = (float*)(ws + 41943040);     // 2 x [32][1024][64] f32 = 16777216 B
  float* Lp = (float*)(ws + 58720256);     // 2 x [32][1024]     f32 =   262144 B
  const bool split = (ws_size >= (size_t)58982400);

  prep_k<<<3072, 256, 0, stream>>>(x, xb, W_attn, WaT, W_proj, WpT);

  gemm_bt<1, 128><<<dim3(24, 32), 256, 0, stream>>>(
      xb, WaT, b_attn, nullptr, Qw, Kw, VtG, 4096, 3072, 1024);

  if (split) {
    attn_k<1><<<1536, 256, 0, stream>>>(Qw, Kw, VtG, AO, Op, Lp);
    norm_k<<<1024, 256, 0, stream>>>(Op, Lp, AO);
  } else {
    attn_k<0><<<1024, 256, 0, stream>>>(Qw, Kw, VtG, AO, nullptr, nullptr);
  }

  gemm_bt<0, 64><<<dim3(16, 32), 256, 0, stream>>>(
      AO, WpT, b_proj, out, nullptr, nullptr, nullptr, 4096, 1024, 1024);
}

// Round 17
// 109.380 us; speedup vs baseline: 1.1053x; 1.0607x over previous
//
#include <hip/hip_runtime.h>
#include <hip/hip_bf16.h>

// B=2, S=2048, E=1024, H=16, D=64. f32 in/out; bf16 MFMA internally.
// R16: attn = R11-exact (proven 49.9us). GEMMs -> 512 threads / 8 waves per block
//      (same 128-row tile, BK=64 split arrays): 24 waves/CU for latency hiding,
//      1 gload16 per thread per array. prep unchanged.

typedef __bf16 bf16;
typedef __bf16 bf16x4 __attribute__((ext_vector_type(4)));
typedef __bf16 bf16x8 __attribute__((ext_vector_type(8)));
typedef float  f32x4  __attribute__((ext_vector_type(4)));

#define MNEG (-1.0e30f)
#define QSCALE 0.1803368801f   // 0.125 * log2(e): folded into Q at GEMM1 epilogue

__device__ __forceinline__ void gload16(const bf16* g, bf16* l) {
  __builtin_amdgcn_global_load_lds((const __attribute__((address_space(1))) void*)g,
                                   (__attribute__((address_space(3))) void*)l, 16, 0, 0);
}

// ---------------- fused prep: x cvt (blocks 0..2047), W_attn^T, W_proj^T ----------------
__global__ __launch_bounds__(256) void prep_k(const float* __restrict__ x, bf16* __restrict__ xb,
                                              const float* __restrict__ Wa, bf16* __restrict__ WaT,
                                              const float* __restrict__ Wp, bf16* __restrict__ WpT) {
  const int bid = blockIdx.x;
  if (bid < 2048) {
    const int i = bid * 256 + threadIdx.x;
    f32x4 a = ((const f32x4*)x)[2 * i], b = ((const f32x4*)x)[2 * i + 1];
    bf16x8 o;
    for (int j = 0; j < 4; ++j) { o[j] = (bf16)a[j]; o[4 + j] = (bf16)b[j]; }
    ((bf16x8*)xb)[i] = o;
    return;
  }
  __shared__ bf16 t[64][68];
  const float* in; bf16* out; int C, cx, cy;
  if (bid < 2816) { in = Wa; out = WaT; C = 3072; const int tt = bid - 2048; cx = tt % 48; cy = tt / 48; }
  else            { in = Wp; out = WpT; C = 1024; const int tt = bid - 2816; cx = tt % 16; cy = tt / 16; }
  const int R = 1024;
  const int c0 = cx * 64, r0 = cy * 64;
  const int lr = threadIdx.x >> 4;
  const int lc = (threadIdx.x & 15) * 4;
  for (int i = 0; i < 4; ++i) {
    int r = lr + i * 16;
    f32x4 v = *(const f32x4*)(in + (size_t)(r0 + r) * C + c0 + lc);
    bf16x4 b;
    for (int j = 0; j < 4; ++j) b[j] = (bf16)v[j];
    *(bf16x4*)&t[r][lc] = b;
  }
  __syncthreads();
  for (int i = 0; i < 4; ++i) {
    int c = lr + i * 16;
    bf16x4 v;
    for (int j = 0; j < 4; ++j) v[j] = t[lc + j][c];
    *(bf16x4*)(out + (size_t)(c0 + c) * R + r0 + lc) = v;
  }
}

// ---------------- GEMM: C[M,N] = A[M,K]*Bt[N,K]^T + bias; 512 thr / 8 waves ----------------
// Tile 128 x BN, BK=64 split arrays. Wave grid: WM x WN, WN = BN/32.
template <int MODE, int BN>
__global__ __launch_bounds__(512) void gemm_bt(const bf16* __restrict__ A,
                                               const bf16* __restrict__ Bt,
                                               const float* __restrict__ bias,
                                               float* __restrict__ C,
                                               bf16* __restrict__ Qo,
                                               bf16* __restrict__ Ko,
                                               bf16* __restrict__ Vo,
                                               int M, int N, int K) {
  constexpr int WN = BN / 32;          // 4 (BN=128) or 2 (BN=64)
  constexpr int WM = 8 / WN;           // 2 or 4
  constexpr int MR = 128 / WM;         // 64 or 32 rows per wave
  constexpr int MT = MR / 16;          // 4 or 2
  __shared__ bf16 As0[128 * 32], As1[128 * 32];
  __shared__ bf16 Bs0[BN * 32],  Bs1[BN * 32];
  const int tid = threadIdx.x;
  const int w = tid >> 6, l = tid & 63;
  const int nx = gridDim.x;
  const int nwg = nx * gridDim.y;
  const int flat = blockIdx.y * nx + blockIdx.x;
  const int swz = (flat & 7) * (nwg >> 3) + (flat >> 3);
  const int m0 = (swz / nx) * 128, n0 = (swz % nx) * BN;
  const int wm = w / WN, wn = w % WN;
  const int fr = l & 15, fg = l >> 4;
  const int grow = tid >> 2;           // 0..127 staging row
  const int gcol = (tid & 3) * 8;      // staging col (elems)

  f32x4 acc[MT][2] = {};

  for (int k0 = 0; k0 < K; k0 += 64) {
    __syncthreads();
    gload16(A + (size_t)(m0 + grow) * K + k0 + gcol,      As0 + 512 * w);
    gload16(A + (size_t)(m0 + grow) * K + k0 + 32 + gcol, As1 + 512 * w);
    if (BN == 128 || w < 4) {
      gload16(Bt + (size_t)(n0 + grow) * K + k0 + gcol,      Bs0 + 512 * w);
      gload16(Bt + (size_t)(n0 + grow) * K + k0 + 32 + gcol, Bs1 + 512 * w);
    }
    __syncthreads();

    bf16x8 af[MT][2], bfv[2][2];
    for (int mt = 0; mt < MT; ++mt) {
      af[mt][0] = *(const bf16x8*)(As0 + (wm * MR + mt * 16 + fr) * 32 + 8 * fg);
      af[mt][1] = *(const bf16x8*)(As1 + (wm * MR + mt * 16 + fr) * 32 + 8 * fg);
    }
    for (int nt = 0; nt < 2; ++nt) {
      bfv[nt][0] = *(const bf16x8*)(Bs0 + (wn * 32 + nt * 16 + fr) * 32 + 8 * fg);
      bfv[nt][1] = *(const bf16x8*)(Bs1 + (wn * 32 + nt * 16 + fr) * 32 + 8 * fg);
    }
    for (int mt = 0; mt < MT; ++mt)
      for (int nt = 0; nt < 2; ++nt) {
        acc[mt][nt] = __builtin_amdgcn_mfma_f32_16x16x32_bf16(af[mt][0], bfv[nt][0], acc[mt][nt], 0, 0, 0);
        acc[mt][nt] = __builtin_amdgcn_mfma_f32_16x16x32_bf16(af[mt][1], bfv[nt][1], acc[mt][nt], 0, 0, 0);
      }
  }

  for (int mt = 0; mt < MT; ++mt) {
    for (int nt = 0; nt < 2; ++nt) {
      const int row0 = m0 + wm * MR + mt * 16 + 4 * fg;
      const int col = n0 + wn * 32 + nt * 16 + fr;
      const float bv = bias[col];
      if (MODE == 0) {
        for (int r = 0; r < 4; ++r)
          C[(size_t)(row0 + r) * N + col] = acc[mt][nt][r] + bv;
      } else {
        const int which = col >> 10, h = (col >> 6) & 15, d = col & 63;
        const int b = row0 >> 11, s = row0 & 2047;
        if (which == 2) {
          bf16x4 vv;
          for (int r = 0; r < 4; ++r) vv[r] = (bf16)(acc[mt][nt][r] + bv);
          *(bf16x4*)(Vo + ((size_t)(b * 16 + h) * 64 + d) * 2048 + s) = vv;
        } else if (which == 0) {
          for (int r = 0; r < 4; ++r)
            Qo[((size_t)(b * 16 + h) * 2048 + s + r) * 64 + d] =
                (bf16)((acc[mt][nt][r] + bv) * QSCALE);
        } else {
          for (int r = 0; r < 4; ++r)
            Ko[((size_t)(b * 16 + h) * 2048 + s + r) * 64 + d] = (bf16)(acc[mt][nt][r] + bv);
        }
      }
    }
  }
}

// ---------------- flash attention: R11-exact (one 64-row q-tile/block, heavy-first) ----------------
__global__ __launch_bounds__(256, 3) void attn_k(const bf16* __restrict__ Qw,
                                                 const bf16* __restrict__ Kw,
                                                 const bf16* __restrict__ VtG,
                                                 bf16* __restrict__ AO) {
  __shared__ bf16 Ks[128 * 72];        // K tile [k][d]            18432 B
  __shared__ bf16 Vt[64 * 136];        // V^T tile [d][k 0..127]   17408 B
  __shared__ bf16 Ps[4 * 16 * 72];     // per-wave P                9216 B
  const int tid = threadIdx.x, w = tid >> 6, l = tid & 63;
  const int bid = blockIdx.x;
  const int bh = ((bid & 7) << 2) | ((bid >> 3) & 3);
  const int qt = 31 - (bid >> 5);             // heavy-first
  const int q0 = qt * 64;
  const int fr = l & 15, fg = l >> 4;
  const size_t base = (size_t)bh * 2048 * 64;
  const int qw0 = q0 + w * 16;
  const int q = qw0 + fr;
  bf16* Pw = Ps + w * 16 * 72;
  const int r8 = tid >> 3, c8 = (tid & 7) * 8;
  const int r16 = tid >> 4, c16 = (tid & 15) * 8;

  bf16x8 qf[2];
  for (int t = 0; t < 2; ++t)
    qf[t] = *(const bf16x8*)(Qw + base + (size_t)(qw0 + fr) * 64 + 32 * t + 8 * fg);

  f32x4 oacc[4] = {};
  float lsum = 0.f;
  bf16x8 kreg[4], vreg[4];

  auto load_tile = [&](int kt) {   // tail overshoot stays in ws, never consumed
    for (int c = 0; c < 4; ++c) {
      kreg[c] = *(const bf16x8*)(Kw + base + (size_t)(kt + r8 + 32 * c) * 64 + c8);
      vreg[c] = *(const bf16x8*)(VtG + base + (size_t)(r16 + 16 * c) * 2048 + kt + c16);
    }
  };
  auto write_tile = [&]() {
    for (int c = 0; c < 4; ++c) {
      *(bf16x8*)(Ks + (r8 + 32 * c) * 72 + c8) = kreg[c];
      *(bf16x8*)(Vt + (r16 + 16 * c) * 136 + c16) = vreg[c];
    }
  };

  load_tile(0);
  write_tile();
  __syncthreads();

  for (int kt = 0; kt <= q0; kt += 128) {
    const bool havenext = (kt + 128 <= q0);
    if (havenext) load_tile(kt + 128);      // T14: issue early

    for (int h = 0; h < 2; ++h) {
      const int kh = kt + 64 * h;
      if (kh > q0) break;

      f32x4 sc[4];
      __builtin_amdgcn_s_setprio(1);
      for (int c = 0; c < 4; ++c) {
        bf16x8 kf0 = *(const bf16x8*)(Ks + (64 * h + c * 16 + fr) * 72 + 8 * fg);
        bf16x8 kf1 = *(const bf16x8*)(Ks + (64 * h + c * 16 + fr) * 72 + 32 + 8 * fg);
        f32x4 z = {};
        z = __builtin_amdgcn_mfma_f32_16x16x32_bf16(kf0, qf[0], z, 0, 0, 0);
        sc[c] = __builtin_amdgcn_mfma_f32_16x16x32_bf16(kf1, qf[1], z, 0, 0, 0);
      }
      __builtin_amdgcn_s_setprio(0);

      const bool need_mask = (kh + 63 > qw0);
      float psum = 0.f;
      for (int c = 0; c < 4; ++c) {
        bf16x4 pb;
        for (int r = 0; r < 4; ++r) {
          float s = sc[c][r];
          if (need_mask && (kh + c * 16 + 4 * fg + r > q)) s = MNEG;
          const float pv = __builtin_amdgcn_exp2f(s);
          psum += pv;
          pb[r] = (bf16)pv;
        }
        *(bf16x4*)(Pw + fr * 72 + c * 16 + 4 * fg) = pb;
      }
      psum += __shfl_xor(psum, 16, 64);
      psum += __shfl_xor(psum, 32, 64);
      lsum += psum;

      asm volatile("" ::: "memory");   // P writes before P reads (in-wave DS order)
      __builtin_amdgcn_s_setprio(1);
      for (int t = 0; t < 2; ++t) {
        bf16x8 pa = *(const bf16x8*)(Pw + fr * 72 + 32 * t + 8 * fg);
        for (int dt = 0; dt < 4; ++dt) {
          bf16x8 vf = *(const bf16x8*)(Vt + (dt * 16 + fr) * 136 + 64 * h + 32 * t + 8 * fg);
          oacc[dt] = __builtin_amdgcn_mfma_f32_16x16x32_bf16(pa, vf, oacc[dt], 0, 0, 0);
        }
      }
      __builtin_amdgcn_s_setprio(0);
      asm volatile("" ::: "memory");   // Pw reused next half
    }

    if (!havenext) break;
    __syncthreads();
    write_tile();                           // T14: write-late
    __syncthreads();
  }

  const int b = bh >> 4, h = bh & 15;
  float linv[4];
  for (int r = 0; r < 4; ++r)
    linv[r] = 1.f / __shfl(lsum, (l & 48) | (4 * fg + r), 64);
  for (int dt = 0; dt < 4; ++dt)
    for (int r = 0; r < 4; ++r) {
      const int qq = qw0 + 4 * fg + r;
      AO[(size_t)(b * 2048 + qq) * 1024 + h * 64 + dt * 16 + fr] =
          (bf16)(oacc[dt][r] * linv[r]);
    }
}

// ---------------- launch ----------------
extern "C" void kernel_launch(void* const* d_in, const int* in_sizes, int n_in,
                              void* d_out, int out_size, void* d_ws, size_t ws_size,
                              hipStream_t stream) {
  const float* x      = (const float*)d_in[0];
  const float* W_attn = (const float*)d_in[1];
  const float* b_attn = (const float*)d_in[2];
  const float* W_proj = (const float*)d_in[3];
  const float* b_proj = (const float*)d_in[4];
  float* out = (float*)d_out;

  char* ws = (char*)d_ws;
  bf16* WaT = (bf16*)(ws);                 // 6291456 B
  bf16* WpT = (bf16*)(ws + 6291456);       // 2097152 B
  bf16* Qw  = (bf16*)(ws + 8388608);       // [B,H,S,D] (pre-scaled by QSCALE)
  bf16* Kw  = (bf16*)(ws + 16777216);      // [B,H,S,D]
  bf16* VtG = (bf16*)(ws + 25165824);      // [B,H,D,S]
  bf16* AO  = (bf16*)(ws + 33554432);      // [B,S,E] bf16; aliased as xb pre-attn
  bf16* xb  = AO;

  prep_k<<<3072, 256, 0, stream>>>(x, xb, W_attn, WaT, W_proj, WpT);

  gemm_bt<1, 128><<<dim3(24, 32), 512, 0, stream>>>(
      xb, WaT, b_attn, nullptr, Qw, Kw, VtG, 4096, 3072, 1024);

  attn_k<<<1024, 256, 0, stream>>>(Qw, Kw, VtG, AO);

  gemm_bt<0, 64><<<dim3(16, 32), 512, 0, stream>>>(
      AO, WpT, b_proj, out, nullptr, nullptr, nullptr, 4096, 1024, 1024);
}